// Round 5
// baseline (1045.985 us; speedup 1.0000x reference)
//
#include <hip/hip_runtime.h>

#define C_CH   256
#define BATCH  8
#define HW     3600
#define CHW    (C_CH*HW)        // 921600
#define NPIX   (BATCH*HW)       // 28800
#define KCONV  4608             // 512*9
#define OHW    480
#define KP     3648             // HW padded to multiple of 64
#define NROWP  3712             // HW padded to multiple of 128
#define XPIX   3844             // 62*62 halo image
#define NT     57               // flash j-steps (3648/64)

typedef __attribute__((ext_vector_type(8))) short s16x8;
typedef __attribute__((ext_vector_type(4))) float f32x4;

__device__ __forceinline__ unsigned short f2bf(float f){
  unsigned int u = __float_as_uint(f);
  u += 0x7FFF + ((u>>16)&1);
  return (unsigned short)(u>>16);
}

__device__ __forceinline__ void gload16(const void* g, void* l){
  __builtin_amdgcn_global_load_lds((const __attribute__((address_space(1))) void*)g,
                                   (__attribute__((address_space(3))) void*)l, 16, 0, 0);
}

// ======================= bf16 MFMA GEMM core (m97-style) ====================
// C[128x128] += A[128xK] * B[128xK]^T, operands K-contiguous, XOR-swizzled LDS.
__device__ __forceinline__ void gemm_core(const char* a0, const char* b0,
                                          size_t lda, size_t ldb, int nkt,
                                          f32x4 acc[4][4]){
  __shared__ __align__(16) char LDS[32768];
  const int tid = threadIdx.x, l = tid & 63, w = tid >> 6;
  char* AsW = LDS + w*1024;
  char* BsW = LDS + 16384 + w*1024;
  const int arow = (w>>1)*64 + (l&15);
  const int brow = (w&1)*64 + (l&15);
  const int kc0 = (((l>>4)*16)      ) ^ ((l&7)<<4);
  const int kc1 = (((l>>4)*16) + 64 ) ^ ((l&7)<<4);
  const char* Ab = LDS;
  const char* Bb = LDS + 16384;
  for (int kt = 0; kt < nkt; ++kt){
#pragma unroll
    for (int i=0;i<4;i++){
      gload16(a0 + (size_t)(i*32)*lda + (size_t)kt*128, AsW + i*4096);
      gload16(b0 + (size_t)(i*32)*ldb + (size_t)kt*128, BsW + i*4096);
    }
    asm volatile("s_waitcnt vmcnt(0)" ::: "memory");
    __syncthreads();
    s16x8 af[4][2], bf[4][2];
#pragma unroll
    for (int f=0;f<4;f++){
      af[f][0] = *(const s16x8*)(Ab + (arow+f*16)*128 + kc0);
      af[f][1] = *(const s16x8*)(Ab + (arow+f*16)*128 + kc1);
      bf[f][0] = *(const s16x8*)(Bb + (brow+f*16)*128 + kc0);
      bf[f][1] = *(const s16x8*)(Bb + (brow+f*16)*128 + kc1);
    }
#pragma unroll
    for (int ks=0;ks<2;ks++)
#pragma unroll
      for (int fm=0;fm<4;fm++)
#pragma unroll
        for (int fn=0;fn<4;fn++)
          acc[fm][fn] = __builtin_amdgcn_mfma_f32_16x16x32_bf16(af[fm][ks], bf[fn][ks], acc[fm][fn], 0,0,0);
    __syncthreads();
  }
}

// ---------------- WVaT[b,i,d] = sum_c VaT[b,i,c]*Wsim[d,c], bf16 out --------
__global__ __launch_bounds__(256) void k_gemm_wva(const unsigned short* __restrict__ VaT,
                                                  const unsigned short* __restrict__ Wsim16,
                                                  unsigned short* __restrict__ WVaT){
  const int tid = threadIdx.x, l = tid&63, w = tid>>6;
  const int b = blockIdx.z;
  const int n0 = blockIdx.x*128, m0 = blockIdx.y*128;
  const int colS = ((tid&7)*16) ^ (((tid>>3)&7)<<4);
  const char* a0 = (const char*)(VaT + (size_t)b*NROWP*256) + (size_t)(m0 + (tid>>3))*512 + colS;
  const char* b0 = (const char*)Wsim16 + (size_t)(n0 + (tid>>3))*512 + colS;
  f32x4 acc[4][4] = {};
  gemm_core(a0, b0, 512, 512, 4, acc);
  unsigned short* ob = WVaT + (size_t)b*NROWP*256;
  const int mb = m0 + (w>>1)*64 + (l>>4)*4;
  const int nb = n0 + (w&1)*64 + (l&15);
#pragma unroll
  for (int fm=0;fm<4;fm++)
#pragma unroll
    for (int fn=0;fn<4;fn++){
      int n = nb + fn*16;
#pragma unroll
      for (int r=0;r<4;r++){
        int m = mb + fm*16 + r;
        if (m < HW) ob[(size_t)m*256 + n] = f2bf(acc[fm][fn][r]);
      }
    }
}

// ---------------- fused flash attention + gate + Xt build -------------------
// side 0: Za = attn(Q=WVaT, K=VbT, V=Vb16), concat VaT -> XtA
// side 1: Zb = attn(Q=VbT, K=WVaT, V=Va16), concat VbT -> XtB
// LDS: K 32K | P 8K. V loaded global->VGPR (no cross-wave reuse).
__global__ __launch_bounds__(256, 3) void flash_attn(const char* __restrict__ WVaT,
                                                  const char* __restrict__ VbT,
                                                  const char* __restrict__ VaT,
                                                  const char* __restrict__ Va16,
                                                  const char* __restrict__ Vb16,
                                                  const float* __restrict__ gw,
                                                  unsigned short* __restrict__ XtA,
                                                  unsigned short* __restrict__ XtB){
  __shared__ __align__(16) char LDS[40960];   // K 32K | P 8K
  const int tid = threadIdx.x, l = tid&63, w = tid>>6;
  const int b = blockIdx.y, side = blockIdx.z;
  const size_t tOff = (size_t)b*NROWP*512;   // bytes for [NROWP][256] bf16
  const size_t vOff = (size_t)b*256*KP*2;
  const char* QT = (side ? VbT  : WVaT) + tOff;
  const char* Kt = (side ? WVaT : VbT ) + tOff;
  const char* Vp = (side ? Va16 : Vb16) + vOff;
  const char* Vc = (side ? VbT  : VaT ) + tOff;
  unsigned short* Xt = (side ? XtB : XtA) + (size_t)b*XPIX*512;
  const int i0 = blockIdx.x*64;

  char* Kls = LDS;
  char* Pls = LDS + 32768;

  // Q rows for this wave in registers
  s16x8 q[8];
  {
    const char* qp = QT + (size_t)(i0 + w*16 + (l&15))*512 + (l>>4)*16;
#pragma unroll
    for (int ks=0;ks<8;ks++) q[ks] = *(const s16x8*)(qp + ks*64);
  }
  float gwv[4];
#pragma unroll
  for (int fn=0;fn<4;fn++) gwv[fn] = gw[w*64 + fn*16 + (l&15)];

  f32x4 acc[4][4] = {};
  f32x4 lac = {0.f,0.f,0.f,0.f};

  auto stageK = [&](int t){
    const char* src = Kt + (size_t)t*32768;
#pragma unroll
    for (int p=0;p<8;p++){
      int row = p*8 + (tid>>5), ch = tid&31;
      gload16(src + (size_t)row*512 + ((ch*16) ^ ((row&7)<<4)), Kls + p*4096 + tid*16);
    }
  };

  stageK(0);
  asm volatile("s_waitcnt vmcnt(0)" ::: "memory");
  __syncthreads();

  // per-lane V base: chan = w*64 + fn*16 + (l&15), j-bytes t*128 + ks*64 + (l>>4)*16
  const char* vrow = Vp + (size_t)(w*64 + (l&15))*(KP*2) + (l>>4)*16;
  const int g = l>>4;

  for (int t=0; t<NT; ++t){
    // ---- V(t) fragments: global -> regs (drained by bar1, covered by QK) ----
    s16x8 bv[2][4];
#pragma unroll
    for (int ks=0;ks<2;ks++)
#pragma unroll
      for (int fn=0;fn<4;fn++)
        bv[ks][fn] = *(const s16x8*)(vrow + (size_t)fn*16*(KP*2) + (size_t)t*128 + ks*64);
    // ---- QK^T: S rows w*16..+16, cols 0..63 ----
    f32x4 sac[4] = {};
#pragma unroll
    for (int ks=0;ks<8;ks++){
      s16x8 bk[4];
#pragma unroll
      for (int fn=0;fn<4;fn++){
        int row = fn*16 + (l&15);
        bk[fn] = *(const s16x8*)(Kls + row*512 + ((ks*64 + (l>>4)*16) ^ ((row&7)<<4)));
      }
#pragma unroll
      for (int fn=0;fn<4;fn++)
        sac[fn] = __builtin_amdgcn_mfma_f32_16x16x32_bf16(q[ks], bk[fn], sac[fn], 0,0,0);
    }
    // ---- exp (no max-sub: |S|<~35), l-acc, P store (octet-XOR swizzle) ----
    const int j0 = t*64;
#pragma unroll
    for (int fn=0;fn<4;fn++){
      int col = fn*16 + (l&15);
      bool jv = (j0 + col) < HW;
#pragma unroll
      for (int r=0;r<4;r++){
        float e = jv ? __expf(sac[fn][r]) : 0.f;
        lac[r] += e;
        int row = w*16 + g*4 + r;
        *(unsigned short*)(Pls + row*128 + ((col*2) ^ (g<<5))) = f2bf(e);
      }
    }
    __syncthreads();                 // bar1: P visible; Kls free; bv drained
    if (t+1 < NT) stageK(t+1);       // K(t+1) load covered by PV
    // ---- PV: O[64 rows][256 cols], wave cols w*64.. ----
#pragma unroll
    for (int ks=0;ks<2;ks++){
      s16x8 ap[4];
#pragma unroll
      for (int fm=0;fm<4;fm++){
        int row = fm*16 + (l&15);
        ap[fm] = *(const s16x8*)(Pls + row*128 + ((ks*64 + (l>>4)*16) ^ ((((l&15)>>2)&3)<<5)));
      }
#pragma unroll
      for (int fm=0;fm<4;fm++)
#pragma unroll
        for (int fn=0;fn<4;fn++)
          acc[fm][fn] = __builtin_amdgcn_mfma_f32_16x16x32_bf16(ap[fm], bv[ks][fn], acc[fm][fn], 0,0,0);
    }
    asm volatile("s_waitcnt vmcnt(0)" ::: "memory");   // K(t+1) in LDS
    __syncthreads();                 // bar2
  }

  // ---- epilogue: l-reduce, gate, mask, write Xt ----
  float* Lred = (float*)(LDS + 32768);       // 64 f32 (1/l per row)
  float* Mls  = Lred + 64;                   // 64 f32 mask
  float* Gp   = Mls + 64;                    // 256 f32 gate partials
#pragma unroll
  for (int r=0;r<4;r++){
    float v = lac[r];
    v += __shfl_xor(v,1); v += __shfl_xor(v,2); v += __shfl_xor(v,4); v += __shfl_xor(v,8);
    if ((l&15)==0) Lred[w*16 + (l>>4)*4 + r] = 1.f / v;
  }
  __syncthreads();
#pragma unroll
  for (int fm=0;fm<4;fm++){
#pragma unroll
    for (int r=0;r<4;r++){
      float v = acc[fm][0][r]*gwv[0] + acc[fm][1][r]*gwv[1]
              + acc[fm][2][r]*gwv[2] + acc[fm][3][r]*gwv[3];
      v += __shfl_xor(v,1); v += __shfl_xor(v,2); v += __shfl_xor(v,4); v += __shfl_xor(v,8);
      if ((l&15)==0) Gp[w*64 + fm*16 + (l>>4)*4 + r] = v;
    }
  }
  __syncthreads();
  if (tid < 64){
    float gt = (Gp[tid] + Gp[64+tid] + Gp[128+tid] + Gp[192+tid]) * Lred[tid];
    Mls[tid] = 1.f/(1.f + __expf(-gt));
  }
  __syncthreads();
  char* Ost = LDS;                           // 64 rows x 512B, linear (Kls dead)
#pragma unroll
  for (int fm=0;fm<4;fm++){
    float4 li = *(const float4*)&Lred[fm*16 + (l>>4)*4];
    float4 mk = *(const float4*)&Mls [fm*16 + (l>>4)*4];
    float s0 = li.x*mk.x, s1 = li.y*mk.y, s2 = li.z*mk.z, s3 = li.w*mk.w;
#pragma unroll
    for (int fn=0;fn<4;fn++){
      int col = w*64 + fn*16 + (l&15);
      int row = fm*16 + (l>>4)*4;
      *(unsigned short*)(Ost + (row+0)*512 + col*2) = f2bf(acc[fm][fn][0]*s0);
      *(unsigned short*)(Ost + (row+1)*512 + col*2) = f2bf(acc[fm][fn][1]*s1);
      *(unsigned short*)(Ost + (row+2)*512 + col*2) = f2bf(acc[fm][fn][2]*s2);
      *(unsigned short*)(Ost + (row+3)*512 + col*2) = f2bf(acc[fm][fn][3]*s3);
    }
  }
  __syncthreads();
  {
    int row = tid>>2, ch = tid&3;
    int p = i0 + row;
    if (p < HW){
      int y = p/60, x = p - y*60;
      char* dst = (char*)Xt + (size_t)((y+1)*62 + (x+1))*1024 + ch*128;
      const char* osrc = Ost + row*512 + ch*128;
      const char* vsrc = Vc + (size_t)p*512 + ch*128;
#pragma unroll
      for (int q8=0;q8<8;q8++) *(uint4*)(dst + q8*16) = *(const uint4*)(osrc + q8*16);
#pragma unroll
      for (int q8=0;q8<8;q8++) *(uint4*)(dst + 512 + q8*16) = *(const uint4*)(vsrc + q8*16);
    }
  }
}

// ---------------- implicit-GEMM 3x3 conv, both convs (z) --------------------
__global__ __launch_bounds__(256) void k_gemm_conv(const unsigned short* __restrict__ WcA,
                                                   const unsigned short* __restrict__ WcB,
                                                   const unsigned short* __restrict__ XtA,
                                                   const unsigned short* __restrict__ XtB,
                                                   float* __restrict__ Ra, float* __restrict__ Rb){
  __shared__ __align__(16) char LDS[32768];
  const int tid = threadIdx.x, l = tid&63, w = tid>>6;
  const unsigned short* Wc = blockIdx.z ? WcB : WcA;
  const unsigned short* Xt = blockIdx.z ? XtB : XtA;
  float* R = blockIdx.z ? Rb : Ra;
  const int n0 = blockIdx.x*128, m0 = blockIdx.y*128;
  const int colS = ((tid&7)*16) ^ (((tid>>3)&7)<<4);
  const int srow = tid>>3;
  const char* a0 = (const char*)Wc + (size_t)(m0+srow)*(KCONV*2) + colS;
  size_t bbase[4];
#pragma unroll
  for (int i=0;i<4;i++){
    int n = n0 + i*32 + srow;
    int bb = n/HW, p = n - bb*HW;
    int y = p/60, x = p - y*60;
    bbase[i] = ((size_t)bb*XPIX + (size_t)(y+1)*62 + (x+1))*1024 + colS;
  }
  char* AsW = LDS + w*1024;
  char* BsW = LDS + 16384 + w*1024;
  const int arow = (w>>1)*64 + (l&15);
  const int brow = (w&1)*64 + (l&15);
  const int kc0 = (((l>>4)*16)      ) ^ ((l&7)<<4);
  const int kc1 = (((l>>4)*16) + 64 ) ^ ((l&7)<<4);
  const char* Ab = LDS;
  const char* Bb = LDS + 16384;
  f32x4 acc[4][4] = {};
  for (int kt = 0; kt < 72; ++kt){
    const int sh = kt>>3;
    const int ci0b = (kt&7)*128;
    const int dy = sh/3 - 1, dx = (sh - (sh/3)*3) - 1;
    const int boff = (dy*62 + dx)*1024 + ci0b;
#pragma unroll
    for (int i=0;i<4;i++){
      gload16(a0 + (size_t)(i*32)*(KCONV*2) + (size_t)kt*128, AsW + i*4096);
      gload16((const char*)Xt + bbase[i] + boff, BsW + i*4096);
    }
    asm volatile("s_waitcnt vmcnt(0)" ::: "memory");
    __syncthreads();
    s16x8 af[4][2], bfr[4][2];
#pragma unroll
    for (int f=0;f<4;f++){
      af[f][0]  = *(const s16x8*)(Ab + (arow+f*16)*128 + kc0);
      af[f][1]  = *(const s16x8*)(Ab + (arow+f*16)*128 + kc1);
      bfr[f][0] = *(const s16x8*)(Bb + (brow+f*16)*128 + kc0);
      bfr[f][1] = *(const s16x8*)(Bb + (brow+f*16)*128 + kc1);
    }
#pragma unroll
    for (int ks=0;ks<2;ks++)
#pragma unroll
      for (int fm=0;fm<4;fm++)
#pragma unroll
        for (int fn=0;fn<4;fn++)
          acc[fm][fn] = __builtin_amdgcn_mfma_f32_16x16x32_bf16(af[fm][ks], bfr[fn][ks], acc[fm][fn], 0,0,0);
    __syncthreads();
  }
  const int mb = m0 + (w>>1)*64 + (l>>4)*4;
  const int nb = n0 + (w&1)*64 + (l&15);
#pragma unroll
  for (int fm=0;fm<4;fm++)
#pragma unroll
    for (int fn=0;fn<4;fn++){
      int n = nb + fn*16;
      int bb = n/HW, p = n - bb*HW;
      float* op = R + (size_t)bb*CHW + (size_t)(mb+fm*16)*HW + p;
#pragma unroll
      for (int r=0;r<4;r++) op[(size_t)r*HW] = acc[fm][fn][r];
    }
}

// ======================= data-movement / small kernels ======================
__global__ __launch_bounds__(256) void zerok(uint4* __restrict__ p, int n){
  int i = blockIdx.x*256 + threadIdx.x;
  if (i < n) p[i] = make_uint4(0,0,0,0);
}

__global__ __launch_bounds__(256) void convert_bf16(const float* __restrict__ in, unsigned short* __restrict__ out, int n){
  int i = blockIdx.x*256 + threadIdx.x;
  if (i < n) out[i] = f2bf(in[i]);
}

// conv weight permute: out[co][sh*512+ci] = in[co][ci*9+sh]
__global__ __launch_bounds__(256) void convw(const float* __restrict__ in, unsigned short* __restrict__ out){
  int idx = blockIdx.x*256 + threadIdx.x;
  int co = idx / KCONV;
  int kp = idx - co*KCONV;
  int sh = kp >> 9, ci = kp & 511;
  out[idx] = f2bf(in[co*KCONV + ci*9 + sh]);
}

// V straight convert with K-pad: out[b*256+c][KP]
__global__ __launch_bounds__(256) void convv(const float* __restrict__ in, unsigned short* __restrict__ out){
  int idx = blockIdx.x*256 + threadIdx.x;
  int row = idx / KP;
  int k = idx - row*KP;
  out[idx] = (k < HW) ? f2bf(in[(size_t)row*HW + k]) : 0;
}

// transpose-convert: in [b][256][3600] f32 -> out [b][NROWP][256] bf16
__global__ __launch_bounds__(256) void convt(const float* __restrict__ in, unsigned short* __restrict__ out){
  __shared__ unsigned short T[64][66];
  const int b = blockIdx.y;
  const int i0 = blockIdx.x*64;
  const float* inb = in + (size_t)b*CHW;
  unsigned short* ob = out + (size_t)b*NROWP*256;
  for (int cc=0; cc<4; ++cc){
    __syncthreads();
    int i = i0 + (threadIdx.x & 63);
    int ic = i < HW ? i : HW-1;
#pragma unroll
    for (int r=0;r<16;r++){
      int cl = (threadIdx.x>>6)*16 + r;
      T[cl][threadIdx.x & 63] = f2bf(inb[(size_t)(cc*64+cl)*HW + ic]);
    }
    __syncthreads();
    int il = threadIdx.x>>2, seg = threadIdx.x&3;
    unsigned short tmp[16];
#pragma unroll
    for (int e=0;e<16;e++) tmp[e] = T[seg*16+e][il];
    *(s16x8*)(ob + (size_t)(i0+il)*256 + cc*64 + seg*16)     = *(const s16x8*)tmp;
    *(s16x8*)(ob + (size_t)(i0+il)*256 + cc*64 + seg*16 + 8) = *(const s16x8*)(tmp+8);
  }
}

// ------------- BN stats: per-channel sum/sumsq over (B,H,W) -----------------
__global__ __launch_bounds__(256) void bn_stats(const float* __restrict__ X, float* __restrict__ sums){
  int co = blockIdx.x;
  float s = 0.f, ss = 0.f;
  for (int i = threadIdx.x; i < NPIX; i += 256){
    int bi = i / HW, p = i - bi*HW;
    float v = X[(size_t)bi*CHW + (size_t)co*HW + p];
    s += v; ss += v*v;
  }
  __shared__ float rs[256], rss[256];
  rs[threadIdx.x] = s; rss[threadIdx.x] = ss; __syncthreads();
  for (int off=128; off>0; off>>=1){
    if (threadIdx.x < off){ rs[threadIdx.x] += rs[threadIdx.x+off]; rss[threadIdx.x] += rss[threadIdx.x+off]; }
    __syncthreads();
  }
  if (threadIdx.x==0){ sums[co] = rs[0]; sums[256+co] = rss[0]; }
}

// ------------- fused BN+ReLU+1x1 cls conv + bias ----------------------------
__global__ __launch_bounds__(256) void cls_kernel(const float* __restrict__ R, const float* __restrict__ sums,
                                                  const float* __restrict__ gamma, const float* __restrict__ beta,
                                                  const float* __restrict__ cw, const float* __restrict__ cb,
                                                  float* __restrict__ Xout){
  __shared__ float red[2][4][64];
  int tx = threadIdx.x & 63, ty = threadIdx.x >> 6;
  int n = blockIdx.x*64 + tx;
  int bi = n / HW, p = n - bi*HW;
  float a0 = 0.f, a1 = 0.f;
  const float invN = 1.f/28800.f;
  for (int c = ty*64; c < ty*64+64; ++c){
    float mean = sums[c]*invN;
    float var  = sums[256+c]*invN - mean*mean;
    float sc   = gamma[c]*rsqrtf(var + 1e-5f);
    float shv  = beta[c] - mean*sc;
    float v = R[(size_t)bi*CHW + (size_t)c*HW + p]*sc + shv;
    v = fmaxf(v, 0.f);
    a0 += v*cw[c]; a1 += v*cw[256+c];
  }
  red[0][ty][tx] = a0; red[1][ty][tx] = a1; __syncthreads();
  if (ty==0){
    float r0 = red[0][0][tx]+red[0][1][tx]+red[0][2][tx]+red[0][3][tx] + cb[0];
    float r1 = red[1][0][tx]+red[1][1][tx]+red[1][2][tx]+red[1][3][tx] + cb[1];
    Xout[((size_t)bi*2 + 0)*HW + p] = r0;
    Xout[((size_t)bi*2 + 1)*HW + p] = r1;
  }
}

// ------------- bilinear 60->480 upsample + sigmoid + stack ------------------
__global__ __launch_bounds__(256) void resize_kernel(const float* __restrict__ X1, const float* __restrict__ X2,
                                                     float* __restrict__ Out){
  int idx = blockIdx.x*256 + threadIdx.x;
  int ox = idx % OHW; int t = idx / OHW;
  int oy = t % OHW;  t /= OHW;
  int nc = t & 1;    t >>= 1;
  int bi = t & 7;    int s = t >> 3;
  const float* X = (s == 0) ? X1 : X2;
  float fy = (oy + 0.5f)*0.125f - 0.5f;
  float fx = (ox + 0.5f)*0.125f - 0.5f;
  float y0f = floorf(fy), x0f = floorf(fx);
  float wy = fy - y0f, wx = fx - x0f;
  int y0 = (int)y0f, x0 = (int)x0f;
  int y1 = min(max(y0+1,0),59), x1 = min(max(x0+1,0),59);
  y0 = min(max(y0,0),59); x0 = min(max(x0,0),59);
  const float* Xp = X + ((size_t)bi*2 + nc)*HW;
  float v00 = Xp[y0*60+x0], v01 = Xp[y0*60+x1];
  float v10 = Xp[y1*60+x0], v11 = Xp[y1*60+x1];
  float v = v00*(1.f-wy)*(1.f-wx) + v01*(1.f-wy)*wx + v10*wy*(1.f-wx) + v11*wy*wx;
  Out[idx] = 1.f/(1.f+__expf(-v));
}

// ============================================================================
extern "C" void kernel_launch(void* const* d_in, const int* in_sizes, int n_in,
                              void* d_out, int out_size, void* d_ws, size_t ws_size,
                              hipStream_t stream){
  const float* Va    = (const float*)d_in[0];
  const float* Vb    = (const float*)d_in[1];
  const float* Wsim  = (const float*)d_in[2];
  const float* gw    = (const float*)d_in[3];
  const float* cwA   = (const float*)d_in[4];
  const float* cwB   = (const float*)d_in[5];
  const float* gA    = (const float*)d_in[6];
  const float* bA    = (const float*)d_in[7];
  const float* gB    = (const float*)d_in[8];
  const float* bB    = (const float*)d_in[9];
  const float* clsAw = (const float*)d_in[10];
  const float* clsAb = (const float*)d_in[11];
  const float* clsBw = (const float*)d_in[12];
  const float* clsBb = (const float*)d_in[13];
  float* out = (float*)d_out;

  char* wsb = (char*)d_ws;
  size_t off = 0;
  auto alloc = [&](size_t bytes)->void*{
    void* pt = wsb + off;
    off += (bytes + 255) & ~(size_t)255;
    return pt;
  };
  // persistent bf16 buffers (~144 MB total, under proven ~165 MB budget)
  unsigned short* Va16   = (unsigned short*)alloc((size_t)8*256*KP*2);      // 14.94 MB } -> Ra
  unsigned short* Vb16   = (unsigned short*)alloc((size_t)8*256*KP*2);      // 14.94 MB }
  unsigned short* VaT16  = (unsigned short*)alloc((size_t)8*NROWP*256*2);   // 15.20 MB } -> Rb
  unsigned short* VbT16  = (unsigned short*)alloc((size_t)8*NROWP*256*2);   // 15.20 MB }
  unsigned short* WVaT16 = (unsigned short*)alloc((size_t)8*NROWP*256*2);   // 15.20 MB -> x1/x2
  unsigned short* Wsim16 = (unsigned short*)alloc((size_t)256*256*2);
  unsigned short* WcA16  = (unsigned short*)alloc((size_t)256*KCONV*2);     // 2.36 MB
  unsigned short* WcB16  = (unsigned short*)alloc((size_t)256*KCONV*2);
  unsigned short* XtA    = (unsigned short*)alloc((size_t)8*XPIX*512*2);    // 31.49 MB
  unsigned short* XtB    = (unsigned short*)alloc((size_t)8*XPIX*512*2);    // 31.49 MB (adjacent)
  float* sumsA= (float*)alloc(512*4);
  float* sumsB= (float*)alloc(512*4);
  // aliases over buffers dead by conv time
  float* Ra = (float*)Va16;                  // 29.49 MB needed; Va16+Vb16 = 29.88 MB
  float* Rb = (float*)VaT16;                 // VaT16+VbT16 = 30.4 MB
  float* x1 = (float*)WVaT16;
  float* x2 = x1 + (size_t)BATCH*2*HW;

  // ---- preprocessing ----
  zerok<<<dim3(15376), dim3(256), 0, stream>>>((uint4*)XtA, 3936256);   // XtA+XtB
  convert_bf16<<<dim3(256), dim3(256), 0, stream>>>(Wsim, Wsim16, 65536);
  convw<<<dim3(4608), dim3(256), 0, stream>>>(cwA, WcA16);
  convw<<<dim3(4608), dim3(256), 0, stream>>>(cwB, WcB16);
  convv<<<dim3(29184), dim3(256), 0, stream>>>(Va, Va16);
  convv<<<dim3(29184), dim3(256), 0, stream>>>(Vb, Vb16);
  convt<<<dim3(57,8), dim3(256), 0, stream>>>(Va, VaT16);
  convt<<<dim3(57,8), dim3(256), 0, stream>>>(Vb, VbT16);
  k_gemm_wva<<<dim3(2,29,8), dim3(256), 0, stream>>>(VaT16, Wsim16, WVaT16);

  // ---- fused attention + gate + Xt build ----
  flash_attn<<<dim3(57,8,2), dim3(256), 0, stream>>>(
      (const char*)WVaT16, (const char*)VbT16, (const char*)VaT16,
      (const char*)Va16, (const char*)Vb16, gw, XtA, XtB);

  // ---- convs + head ----
  k_gemm_conv<<<dim3(225,2,2), dim3(256), 0, stream>>>(WcA16, WcB16, XtA, XtB, Ra, Rb);
  bn_stats<<<dim3(256), dim3(256), 0, stream>>>(Ra, sumsA);
  bn_stats<<<dim3(256), dim3(256), 0, stream>>>(Rb, sumsB);
  cls_kernel<<<dim3(450), dim3(256), 0, stream>>>(Ra, sumsA, gA, bA, clsAw, clsAb, x1);
  cls_kernel<<<dim3(450), dim3(256), 0, stream>>>(Rb, sumsB, gB, bB, clsBw, clsBb, x2);
  resize_kernel<<<dim3(28800), dim3(256), 0, stream>>>(x1, x2, out);
}

// Round 6
// 843.458 us; speedup vs baseline: 1.2401x; 1.2401x over previous
//
#include <hip/hip_runtime.h>

#define C_CH   256
#define BATCH  8
#define HW     3600
#define CHW    (C_CH*HW)        // 921600
#define NPIX   (BATCH*HW)       // 28800
#define KCONV  4608             // 512*9
#define OHW    480
#define KP     3648             // HW padded to multiple of 64
#define TR     3840             // transposed-buffer rows (15*256)
#define XPIX   3844             // 62*62 halo image
#define NTJ    57               // flash j-steps (3648/64)

typedef __attribute__((ext_vector_type(8))) short s16x8;
typedef __attribute__((ext_vector_type(4))) float f32x4;
typedef __attribute__((ext_vector_type(16))) float f32x16;

__device__ __forceinline__ unsigned short f2bf(float f){
  unsigned int u = __float_as_uint(f);
  u += 0x7FFF + ((u>>16)&1);
  return (unsigned short)(u>>16);
}

__device__ __forceinline__ void gload16(const void* g, void* l){
  __builtin_amdgcn_global_load_lds((const __attribute__((address_space(1))) void*)g,
                                   (__attribute__((address_space(3))) void*)l, 16, 0, 0);
}

// ======================= bf16 MFMA GEMM core (m97-style) ====================
__device__ __forceinline__ void gemm_core(const char* a0, const char* b0,
                                          size_t lda, size_t ldb, int nkt,
                                          f32x4 acc[4][4]){
  __shared__ __align__(16) char LDS[32768];
  const int tid = threadIdx.x, l = tid & 63, w = tid >> 6;
  char* AsW = LDS + w*1024;
  char* BsW = LDS + 16384 + w*1024;
  const int arow = (w>>1)*64 + (l&15);
  const int brow = (w&1)*64 + (l&15);
  const int kc0 = (((l>>4)*16)      ) ^ ((l&7)<<4);
  const int kc1 = (((l>>4)*16) + 64 ) ^ ((l&7)<<4);
  const char* Ab = LDS;
  const char* Bb = LDS + 16384;
  for (int kt = 0; kt < nkt; ++kt){
#pragma unroll
    for (int i=0;i<4;i++){
      gload16(a0 + (size_t)(i*32)*lda + (size_t)kt*128, AsW + i*4096);
      gload16(b0 + (size_t)(i*32)*ldb + (size_t)kt*128, BsW + i*4096);
    }
    asm volatile("s_waitcnt vmcnt(0)" ::: "memory");
    __syncthreads();
    s16x8 af[4][2], bf[4][2];
#pragma unroll
    for (int f=0;f<4;f++){
      af[f][0] = *(const s16x8*)(Ab + (arow+f*16)*128 + kc0);
      af[f][1] = *(const s16x8*)(Ab + (arow+f*16)*128 + kc1);
      bf[f][0] = *(const s16x8*)(Bb + (brow+f*16)*128 + kc0);
      bf[f][1] = *(const s16x8*)(Bb + (brow+f*16)*128 + kc1);
    }
#pragma unroll
    for (int ks=0;ks<2;ks++)
#pragma unroll
      for (int fm=0;fm<4;fm++)
#pragma unroll
        for (int fn=0;fn<4;fn++)
          acc[fm][fn] = __builtin_amdgcn_mfma_f32_16x16x32_bf16(af[fm][ks], bf[fn][ks], acc[fm][fn], 0,0,0);
    __syncthreads();
  }
}

// ---------------- WVaT[b,i,d] = sum_c VaT[b,i,c]*Wsim[d,c], bf16 out --------
__global__ __launch_bounds__(256) void k_gemm_wva(const unsigned short* __restrict__ VaT,
                                                  const unsigned short* __restrict__ Wsim16,
                                                  unsigned short* __restrict__ WVaT){
  const int tid = threadIdx.x, l = tid&63, w = tid>>6;
  const int b = blockIdx.z;
  const int n0 = blockIdx.x*128, m0 = blockIdx.y*128;
  const int colS = ((tid&7)*16) ^ (((tid>>3)&7)<<4);
  const char* a0 = (const char*)(VaT + (size_t)b*TR*256) + (size_t)(m0 + (tid>>3))*512 + colS;
  const char* b0 = (const char*)Wsim16 + (size_t)(n0 + (tid>>3))*512 + colS;
  f32x4 acc[4][4] = {};
  gemm_core(a0, b0, 512, 512, 4, acc);
  unsigned short* ob = WVaT + (size_t)b*TR*256;
  const int mb = m0 + (w>>1)*64 + (l>>4)*4;
  const int nb = n0 + (w&1)*64 + (l&15);
#pragma unroll
  for (int fm=0;fm<4;fm++)
#pragma unroll
    for (int fn=0;fn<4;fn++){
      int n = nb + fn*16;
#pragma unroll
      for (int r=0;r<4;r++){
        int m = mb + fm*16 + r;
        if (m < HW) ob[(size_t)m*256 + n] = f2bf(acc[fm][fn][r]);
      }
    }
}

// ---------------- fused flash attention + gate + Xt build (v2) --------------
// Swapped QK^T (S^T = mfma(K,Q)) so P stays in registers; 32x32x16 MFMA.
// 8 waves, 256 q-rows/block, 32 q/wave. K/V double-buffered in LDS.
// side 0: Za = attn(Q=WVaT, K=VbT, V=Vb16), concat VaT -> XtA
// side 1: Zb = attn(Q=VbT, K=WVaT, V=Va16), concat VbT -> XtB
__global__ __launch_bounds__(512, 2) void flash2(const char* __restrict__ WVaT,
                                                 const char* __restrict__ VbT,
                                                 const char* __restrict__ VaT,
                                                 const char* __restrict__ Va16,
                                                 const char* __restrict__ Vb16,
                                                 const float* __restrict__ gw,
                                                 unsigned short* __restrict__ XtA,
                                                 unsigned short* __restrict__ XtB){
  extern __shared__ __align__(16) char LDS[];   // K dbuf 64K | V dbuf 64K | Linv 1K
  const int tid = threadIdx.x;
  const int l = tid & 63, w = tid >> 6;        // 8 waves
  const int lq = l & 31, g = l >> 5;
  // XCD-aware decode (240 blocks): batch b pinned to XCD b
  const int f = blockIdx.x;
  const int b = f & 7;
  const int k2 = f >> 3;                       // 0..29
  const int side = k2 / 15;
  const int qb = k2 - side*15;
  const size_t tOff = (size_t)b*TR*512;
  const size_t vOff = (size_t)b*256*(KP*2);
  const char* QT = (side ? VbT  : WVaT) + tOff;
  const char* Kt = (side ? WVaT : VbT ) + tOff;
  const char* Vp = (side ? Va16 : Vb16) + vOff;
  const char* Vc = (side ? VbT  : VaT ) + tOff;
  unsigned short* Xt = (side ? XtB : XtA) + (size_t)b*XPIX*512;
  const int p0 = qb*256;

  // ---- stage Q block (256 rows x 512B) through LDS, coalesced ----
#pragma unroll
  for (int p=0;p<16;p++){
    int row = p*16 + (tid>>5), ch = tid&31;
    gload16(QT + (size_t)(p0+row)*512 + ((ch*16) ^ ((row&31)<<4)), LDS + p*8192 + tid*16);
  }
  asm volatile("s_waitcnt vmcnt(0)" ::: "memory");
  __syncthreads();
  s16x8 qf[16];            // B-operand: lane holds col q=lq, k = st*16 + g*8 + e
#pragma unroll
  for (int st=0; st<16; ++st)
    qf[st] = *(const s16x8*)(LDS + (size_t)(w*32+lq)*512 + ((st*32 + g*16) ^ (lq<<4)));
  __syncthreads();

  auto stageKV = [&](int t, int o){
    char* Kd = LDS + o*32768;
    char* Vd = LDS + 65536 + o*32768;
#pragma unroll
    for (int p=0;p<4;p++){
      int row = p*16 + (tid>>5), ch = tid&31;
      gload16(Kt + (size_t)(t*64+row)*512 + ((ch*16) ^ ((row&31)<<4)), Kd + p*8192 + tid*16);
    }
#pragma unroll
    for (int p=0;p<4;p++){
      int c = p*64 + (tid>>3), ch = tid&7;
      gload16(Vp + (size_t)c*(KP*2) + (size_t)t*128 + ((ch*16) ^ ((c&7)<<4)), Vd + p*8192 + tid*16);
    }
  };

  stageKV(0, 0);
  asm volatile("s_waitcnt vmcnt(0)" ::: "memory");
  __syncthreads();

  f32x16 acc[8] = {};      // O[q][c]: col c = ct*32+lq, row q = (r&3)+8*(r>>2)+4*g
  float lac = 0.f;

  for (int t=0; t<NTJ; ++t){
    const int o = t&1;
    if (t+1 < NTJ) stageKV(t+1, o^1);
    const char* Kb = LDS + o*32768;
    const char* Vbuf = LDS + 65536 + o*32768;
#pragma unroll
    for (int jt=0;jt<2;jt++){
      // ---- S^T[j][q] = mfma(A=K, B=Q) over d=256 ----
      f32x16 sac = {};
#pragma unroll
      for (int st=0;st<16;st++){
        s16x8 kf = *(const s16x8*)(Kb + (size_t)(jt*32+lq)*512 + ((st*32+g*16) ^ (lq<<4)));
        sac = __builtin_amdgcn_mfma_f32_32x32x16_bf16(kf, qf[st], sac, 0,0,0);
      }
      // ---- exp in-register (no max-sub: |S| < ~35), j-mask, l-acc ----
      float pe[16];
      const int jb = t*64 + jt*32 + 4*g;
#pragma unroll
      for (int r=0;r<16;r++){
        int j = jb + (r&3) + 8*(r>>2);
        float e = (j < HW) ? __expf(sac[r]) : 0.f;
        lac += e; pe[r] = e;
      }
      // ---- pack P to bf16 A-frags via cvt_pk + half-exchange; PV ----
#pragma unroll
      for (int kp=0;kp<2;kp++){
        unsigned u0,u1,u2,u3;
        asm("v_cvt_pk_bf16_f32 %0, %1, %2" : "=v"(u0) : "v"(pe[8*kp+0]), "v"(pe[8*kp+1]));
        asm("v_cvt_pk_bf16_f32 %0, %1, %2" : "=v"(u1) : "v"(pe[8*kp+2]), "v"(pe[8*kp+3]));
        asm("v_cvt_pk_bf16_f32 %0, %1, %2" : "=v"(u2) : "v"(pe[8*kp+4]), "v"(pe[8*kp+5]));
        asm("v_cvt_pk_bf16_f32 %0, %1, %2" : "=v"(u3) : "v"(pe[8*kp+6]), "v"(pe[8*kp+7]));
        unsigned s0 = (unsigned)__shfl_xor((int)u0,32), s1 = (unsigned)__shfl_xor((int)u1,32);
        unsigned s2 = (unsigned)__shfl_xor((int)u2,32), s3 = (unsigned)__shfl_xor((int)u3,32);
        uint4 pw;
        pw.x = g ? s2 : u0;  pw.y = g ? s3 : u1;
        pw.z = g ? u2 : s0;  pw.w = g ? u3 : s1;
        s16x8 pf = *(s16x8*)&pw;                 // A-frag: row q=lq, k=j
        const int ks = jt*2 + kp;
#pragma unroll
        for (int ct=0;ct<8;ct++){
          s16x8 vf = *(const s16x8*)(Vbuf + (size_t)(ct*32+lq)*128 + ((ks*32+g*16) ^ ((lq&7)<<4)));
          acc[ct] = __builtin_amdgcn_mfma_f32_32x32x16_bf16(pf, vf, acc[ct], 0,0,0);
        }
      }
    }
    asm volatile("s_waitcnt vmcnt(0)" ::: "memory");
    __syncthreads();
  }

  // ---- epilogue: l, gate, mask, Xt ----
  float lt = lac + __shfl_xor(lac, 32);        // partner half holds other j's of same q
  float invl = 1.f/lt;
  float* Linv = (float*)(LDS + 131072);
  if (!g) Linv[w*32 + lq] = invl;
  float gwv[8];
#pragma unroll
  for (int ct=0;ct<8;ct++) gwv[ct] = gw[ct*32 + lq];
  __syncthreads();                             // Linv visible; K/V reads done
  unsigned short* Ost = (unsigned short*)LDS;  // 256 rows x 512B, linear
#pragma unroll
  for (int r=0;r<16;r++){
    float p = 0.f;
#pragma unroll
    for (int ct=0;ct<8;ct++) p += acc[ct][r]*gwv[ct];
    p += __shfl_xor(p,1); p += __shfl_xor(p,2); p += __shfl_xor(p,4);
    p += __shfl_xor(p,8); p += __shfl_xor(p,16);
    int ql = 4*g + (r&3) + 8*(r>>2);
    float il = Linv[w*32 + ql];
    float mk = 1.f/(1.f + __expf(-p*il));
    float sc = il*mk;
#pragma unroll
    for (int ct=0;ct<8;ct++)
      Ost[(size_t)(w*32+ql)*256 + ct*32 + lq] = f2bf(acc[ct][r]*sc);
  }
  __syncthreads();
#pragma unroll
  for (int pass=0; pass<2; ++pass){
    int unit = tid + pass*512;
    int row = unit>>2, qt = unit&3;
    int p = p0 + row;
    if (p < HW){
      int y = p/60, x = p - y*60;
      char* dst = (char*)Xt + (size_t)((y+1)*62 + (x+1))*1024 + qt*256;
      const char* src = (qt < 2) ? (const char*)LDS + (size_t)row*512 + qt*256
                                 : Vc + (size_t)p*512 + (qt-2)*256;
#pragma unroll
      for (int q8=0;q8<16;q8++) *(uint4*)(dst + q8*16) = *(const uint4*)(src + q8*16);
    }
  }
}

// ---------------- implicit-GEMM 3x3 conv, both convs (z) --------------------
__global__ __launch_bounds__(256) void k_gemm_conv(const unsigned short* __restrict__ WcA,
                                                   const unsigned short* __restrict__ WcB,
                                                   const unsigned short* __restrict__ XtA,
                                                   const unsigned short* __restrict__ XtB,
                                                   float* __restrict__ Ra, float* __restrict__ Rb){
  __shared__ __align__(16) char LDS[32768];
  const int tid = threadIdx.x, l = tid&63, w = tid>>6;
  const unsigned short* Wc = blockIdx.z ? WcB : WcA;
  const unsigned short* Xt = blockIdx.z ? XtB : XtA;
  float* R = blockIdx.z ? Rb : Ra;
  const int n0 = blockIdx.x*128, m0 = blockIdx.y*128;
  const int colS = ((tid&7)*16) ^ (((tid>>3)&7)<<4);
  const int srow = tid>>3;
  const char* a0 = (const char*)Wc + (size_t)(m0+srow)*(KCONV*2) + colS;
  size_t bbase[4];
#pragma unroll
  for (int i=0;i<4;i++){
    int n = n0 + i*32 + srow;
    int bb = n/HW, p = n - bb*HW;
    int y = p/60, x = p - y*60;
    bbase[i] = ((size_t)bb*XPIX + (size_t)(y+1)*62 + (x+1))*1024 + colS;
  }
  char* AsW = LDS + w*1024;
  char* BsW = LDS + 16384 + w*1024;
  const int arow = (w>>1)*64 + (l&15);
  const int brow = (w&1)*64 + (l&15);
  const int kc0 = (((l>>4)*16)      ) ^ ((l&7)<<4);
  const int kc1 = (((l>>4)*16) + 64 ) ^ ((l&7)<<4);
  const char* Ab = LDS;
  const char* Bb = LDS + 16384;
  f32x4 acc[4][4] = {};
  for (int kt = 0; kt < 72; ++kt){
    const int sh = kt>>3;
    const int ci0b = (kt&7)*128;
    const int dy = sh/3 - 1, dx = (sh - (sh/3)*3) - 1;
    const int boff = (dy*62 + dx)*1024 + ci0b;
#pragma unroll
    for (int i=0;i<4;i++){
      gload16(a0 + (size_t)(i*32)*(KCONV*2) + (size_t)kt*128, AsW + i*4096);
      gload16((const char*)Xt + bbase[i] + boff, BsW + i*4096);
    }
    asm volatile("s_waitcnt vmcnt(0)" ::: "memory");
    __syncthreads();
    s16x8 af[4][2], bfr[4][2];
#pragma unroll
    for (int f=0;f<4;f++){
      af[f][0]  = *(const s16x8*)(Ab + (arow+f*16)*128 + kc0);
      af[f][1]  = *(const s16x8*)(Ab + (arow+f*16)*128 + kc1);
      bfr[f][0] = *(const s16x8*)(Bb + (brow+f*16)*128 + kc0);
      bfr[f][1] = *(const s16x8*)(Bb + (brow+f*16)*128 + kc1);
    }
#pragma unroll
    for (int ks=0;ks<2;ks++)
#pragma unroll
      for (int fm=0;fm<4;fm++)
#pragma unroll
        for (int fn=0;fn<4;fn++)
          acc[fm][fn] = __builtin_amdgcn_mfma_f32_16x16x32_bf16(af[fm][ks], bfr[fn][ks], acc[fm][fn], 0,0,0);
    __syncthreads();
  }
  const int mb = m0 + (w>>1)*64 + (l>>4)*4;
  const int nb = n0 + (w&1)*64 + (l&15);
#pragma unroll
  for (int fm=0;fm<4;fm++)
#pragma unroll
    for (int fn=0;fn<4;fn++){
      int n = nb + fn*16;
      int bb = n/HW, p = n - bb*HW;
      float* op = R + (size_t)bb*CHW + (size_t)(mb+fm*16)*HW + p;
#pragma unroll
      for (int r=0;r<4;r++) op[(size_t)r*HW] = acc[fm][fn][r];
    }
}

// ======================= data-movement / small kernels ======================
__global__ __launch_bounds__(256) void zerok(uint4* __restrict__ p, int n){
  int i = blockIdx.x*256 + threadIdx.x;
  if (i < n) p[i] = make_uint4(0,0,0,0);
}

__global__ __launch_bounds__(256) void convert_bf16(const float* __restrict__ in, unsigned short* __restrict__ out, int n){
  int i = blockIdx.x*256 + threadIdx.x;
  if (i < n) out[i] = f2bf(in[i]);
}

// conv weight permute: out[co][sh*512+ci] = in[co][ci*9+sh]
__global__ __launch_bounds__(256) void convw(const float* __restrict__ in, unsigned short* __restrict__ out){
  int idx = blockIdx.x*256 + threadIdx.x;
  int co = idx / KCONV;
  int kp = idx - co*KCONV;
  int sh = kp >> 9, ci = kp & 511;
  out[idx] = f2bf(in[co*KCONV + ci*9 + sh]);
}

// V straight convert with K-pad: out[b*256+c][KP]
__global__ __launch_bounds__(256) void convv(const float* __restrict__ in, unsigned short* __restrict__ out){
  int idx = blockIdx.x*256 + threadIdx.x;
  int row = idx / KP;
  int k = idx - row*KP;
  out[idx] = (k < HW) ? f2bf(in[(size_t)row*HW + k]) : 0;
}

// transpose-convert: in [b][256][3600] f32 -> out [b][TR][256] bf16
__global__ __launch_bounds__(256) void convt(const float* __restrict__ in, unsigned short* __restrict__ out){
  __shared__ unsigned short T[64][66];
  const int b = blockIdx.y;
  const int i0 = blockIdx.x*64;
  const float* inb = in + (size_t)b*CHW;
  unsigned short* ob = out + (size_t)b*TR*256;
  for (int cc=0; cc<4; ++cc){
    __syncthreads();
    int i = i0 + (threadIdx.x & 63);
    int ic = i < HW ? i : HW-1;
#pragma unroll
    for (int r=0;r<16;r++){
      int cl = (threadIdx.x>>6)*16 + r;
      T[cl][threadIdx.x & 63] = f2bf(inb[(size_t)(cc*64+cl)*HW + ic]);
    }
    __syncthreads();
    int il = threadIdx.x>>2, seg = threadIdx.x&3;
    unsigned short tmp[16];
#pragma unroll
    for (int e=0;e<16;e++) tmp[e] = T[seg*16+e][il];
    *(s16x8*)(ob + (size_t)(i0+il)*256 + cc*64 + seg*16)     = *(const s16x8*)tmp;
    *(s16x8*)(ob + (size_t)(i0+il)*256 + cc*64 + seg*16 + 8) = *(const s16x8*)(tmp+8);
  }
}

// ------------- BN stats: per-channel sum/sumsq over (B,H,W) -----------------
__global__ __launch_bounds__(256) void bn_stats(const float* __restrict__ X, float* __restrict__ sums){
  int co = blockIdx.x;
  float s = 0.f, ss = 0.f;
  for (int i = threadIdx.x; i < NPIX; i += 256){
    int bi = i / HW, p = i - bi*HW;
    float v = X[(size_t)bi*CHW + (size_t)co*HW + p];
    s += v; ss += v*v;
  }
  __shared__ float rs[256], rss[256];
  rs[threadIdx.x] = s; rss[threadIdx.x] = ss; __syncthreads();
  for (int off=128; off>0; off>>=1){
    if (threadIdx.x < off){ rs[threadIdx.x] += rs[threadIdx.x+off]; rss[threadIdx.x] += rss[threadIdx.x+off]; }
    __syncthreads();
  }
  if (threadIdx.x==0){ sums[co] = rs[0]; sums[256+co] = rss[0]; }
}

// ------------- fused BN+ReLU+1x1 cls conv + bias ----------------------------
__global__ __launch_bounds__(256) void cls_kernel(const float* __restrict__ R, const float* __restrict__ sums,
                                                  const float* __restrict__ gamma, const float* __restrict__ beta,
                                                  const float* __restrict__ cw, const float* __restrict__ cb,
                                                  float* __restrict__ Xout){
  __shared__ float red[2][4][64];
  int tx = threadIdx.x & 63, ty = threadIdx.x >> 6;
  int n = blockIdx.x*64 + tx;
  int bi = n / HW, p = n - bi*HW;
  float a0 = 0.f, a1 = 0.f;
  const float invN = 1.f/28800.f;
  for (int c = ty*64; c < ty*64+64; ++c){
    float mean = sums[c]*invN;
    float var  = sums[256+c]*invN - mean*mean;
    float sc   = gamma[c]*rsqrtf(var + 1e-5f);
    float shv  = beta[c] - mean*sc;
    float v = R[(size_t)bi*CHW + (size_t)c*HW + p]*sc + shv;
    v = fmaxf(v, 0.f);
    a0 += v*cw[c]; a1 += v*cw[256+c];
  }
  red[0][ty][tx] = a0; red[1][ty][tx] = a1; __syncthreads();
  if (ty==0){
    float r0 = red[0][0][tx]+red[0][1][tx]+red[0][2][tx]+red[0][3][tx] + cb[0];
    float r1 = red[1][0][tx]+red[1][1][tx]+red[1][2][tx]+red[1][3][tx] + cb[1];
    Xout[((size_t)bi*2 + 0)*HW + p] = r0;
    Xout[((size_t)bi*2 + 1)*HW + p] = r1;
  }
}

// ------------- bilinear 60->480 upsample + sigmoid + stack ------------------
__global__ __launch_bounds__(256) void resize_kernel(const float* __restrict__ X1, const float* __restrict__ X2,
                                                     float* __restrict__ Out){
  int idx = blockIdx.x*256 + threadIdx.x;
  int ox = idx % OHW; int t = idx / OHW;
  int oy = t % OHW;  t /= OHW;
  int nc = t & 1;    t >>= 1;
  int bi = t & 7;    int s = t >> 3;
  const float* X = (s == 0) ? X1 : X2;
  float fy = (oy + 0.5f)*0.125f - 0.5f;
  float fx = (ox + 0.5f)*0.125f - 0.5f;
  float y0f = floorf(fy), x0f = floorf(fx);
  float wy = fy - y0f, wx = fx - x0f;
  int y0 = (int)y0f, x0 = (int)x0f;
  int y1 = min(max(y0+1,0),59), x1 = min(max(x0+1,0),59);
  y0 = min(max(y0,0),59); x0 = min(max(x0,0),59);
  const float* Xp = X + ((size_t)bi*2 + nc)*HW;
  float v00 = Xp[y0*60+x0], v01 = Xp[y0*60+x1];
  float v10 = Xp[y1*60+x0], v11 = Xp[y1*60+x1];
  float v = v00*(1.f-wy)*(1.f-wx) + v01*(1.f-wy)*wx + v10*wy*(1.f-wx) + v11*wy*wx;
  Out[idx] = 1.f/(1.f+__expf(-v));
}

// ============================================================================
extern "C" void kernel_launch(void* const* d_in, const int* in_sizes, int n_in,
                              void* d_out, int out_size, void* d_ws, size_t ws_size,
                              hipStream_t stream){
  const float* Va    = (const float*)d_in[0];
  const float* Vb    = (const float*)d_in[1];
  const float* Wsim  = (const float*)d_in[2];
  const float* gw    = (const float*)d_in[3];
  const float* cwA   = (const float*)d_in[4];
  const float* cwB   = (const float*)d_in[5];
  const float* gA    = (const float*)d_in[6];
  const float* bA    = (const float*)d_in[7];
  const float* gB    = (const float*)d_in[8];
  const float* bB    = (const float*)d_in[9];
  const float* clsAw = (const float*)d_in[10];
  const float* clsAb = (const float*)d_in[11];
  const float* clsBw = (const float*)d_in[12];
  const float* clsBb = (const float*)d_in[13];
  float* out = (float*)d_out;

  char* wsb = (char*)d_ws;
  size_t off = 0;
  auto alloc = [&](size_t bytes)->void*{
    void* pt = wsb + off;
    off += (bytes + 255) & ~(size_t)255;
    return pt;
  };
  // persistent bf16 buffers (~143 MB total, under proven ~165 MB budget)
  unsigned short* Va16   = (unsigned short*)alloc((size_t)8*256*KP*2);      // 14.94 MB } -> Ra
  unsigned short* Vb16   = (unsigned short*)alloc((size_t)8*256*KP*2);      // 14.94 MB }
  unsigned short* VaT16  = (unsigned short*)alloc((size_t)8*TR*256*2);      // 15.73 MB } -> Rb
  unsigned short* VbT16  = (unsigned short*)alloc((size_t)8*TR*256*2);      // 15.73 MB }
  unsigned short* WVaT16 = (unsigned short*)alloc((size_t)8*TR*256*2);      // 15.73 MB -> x1/x2
  unsigned short* Wsim16 = (unsigned short*)alloc((size_t)256*256*2);
  unsigned short* WcA16  = (unsigned short*)alloc((size_t)256*KCONV*2);     // 2.36 MB
  unsigned short* WcB16  = (unsigned short*)alloc((size_t)256*KCONV*2);
  unsigned short* XtA    = (unsigned short*)alloc((size_t)8*XPIX*512*2);    // 31.49 MB
  unsigned short* XtB    = (unsigned short*)alloc((size_t)8*XPIX*512*2);    // 31.49 MB (adjacent)
  float* sumsA= (float*)alloc(512*4);
  float* sumsB= (float*)alloc(512*4);
  // aliases over buffers dead by conv time
  float* Ra = (float*)Va16;
  float* Rb = (float*)VaT16;
  float* x1 = (float*)WVaT16;
  float* x2 = x1 + (size_t)BATCH*2*HW;

  // ---- preprocessing ----
  zerok<<<dim3(15376), dim3(256), 0, stream>>>((uint4*)XtA, 3936256);   // XtA+XtB
  convert_bf16<<<dim3(256), dim3(256), 0, stream>>>(Wsim, Wsim16, 65536);
  convw<<<dim3(4608), dim3(256), 0, stream>>>(cwA, WcA16);
  convw<<<dim3(4608), dim3(256), 0, stream>>>(cwB, WcB16);
  convv<<<dim3(29184), dim3(256), 0, stream>>>(Va, Va16);
  convv<<<dim3(29184), dim3(256), 0, stream>>>(Vb, Vb16);
  convt<<<dim3(57,8), dim3(256), 0, stream>>>(Va, VaT16);
  convt<<<dim3(57,8), dim3(256), 0, stream>>>(Vb, VbT16);
  k_gemm_wva<<<dim3(2,29,8), dim3(256), 0, stream>>>(VaT16, Wsim16, WVaT16);

  // ---- fused attention + gate + Xt build ----
  flash2<<<dim3(240), dim3(512), 132096, stream>>>(
      (const char*)WVaT16, (const char*)VbT16, (const char*)VaT16,
      (const char*)Va16, (const char*)Vb16, gw, XtA, XtB);

  // ---- convs + head ----
  k_gemm_conv<<<dim3(225,2,2), dim3(256), 0, stream>>>(WcA16, WcB16, XtA, XtB, Ra, Rb);
  bn_stats<<<dim3(256), dim3(256), 0, stream>>>(Ra, sumsA);
  bn_stats<<<dim3(256), dim3(256), 0, stream>>>(Rb, sumsB);
  cls_kernel<<<dim3(450), dim3(256), 0, stream>>>(Ra, sumsA, gA, bA, clsAw, clsAb, x1);
  cls_kernel<<<dim3(450), dim3(256), 0, stream>>>(Rb, sumsB, gB, bB, clsBw, clsBb, x2);
  resize_kernel<<<dim3(28800), dim3(256), 0, stream>>>(x1, x2, out);
}